// Round 11
// baseline (696.554 us; speedup 1.0000x reference)
//
#include <hip/hip_runtime.h>
#include <math.h>

#define HID 64
#define LR_ATT 0.2f
#define LR_ACT 0.01f
#define SCAN_NT 1024

// ---------------- CSR build (once per call; graph shared by all 3 layers) ----------------

__global__ __launch_bounds__(256) void count_kernel(
    const int* __restrict__ dst, int* __restrict__ counts, int E)
{
    int i = blockIdx.x * blockDim.x + threadIdx.x;
    int stride = gridDim.x * blockDim.x;
    for (; i < E; i += stride) atomicAdd(&counts[dst[i]], 1);
}

// Single-block exclusive scan of counts[0..n) -> offsets[0..n], plus cursor copy.
__global__ __launch_bounds__(SCAN_NT) void scan_kernel(
    const int* __restrict__ counts, int* __restrict__ offsets,
    int* __restrict__ cursor, int n)
{
    __shared__ int sdata[SCAN_NT];
    const int t = threadIdx.x;
    const int C = (n + SCAN_NT - 1) / SCAN_NT;
    const int beg = t * C;
    const int end = min(n, beg + C);

    int local = 0;
    for (int i = beg; i < end; ++i) local += counts[i];
    sdata[t] = local;
    __syncthreads();
    // Hillis-Steele inclusive scan
    for (int off = 1; off < SCAN_NT; off <<= 1) {
        int v = (t >= off) ? sdata[t - off] : 0;
        __syncthreads();
        sdata[t] += v;
        __syncthreads();
    }
    int run = sdata[t] - local;  // exclusive base for this thread's chunk
    for (int i = beg; i < end; ++i) {
        offsets[i] = run;
        cursor[i]  = run;
        run += counts[i];
    }
    if (end == n && beg <= n) offsets[n] = run;  // total == E
}

// Random 4B writes done as atomicExch: memory-side op, no L2 line
// allocation/dirty-line write-back amplification (plain stores cost 64B/line).
__global__ __launch_bounds__(256) void scatter_kernel(
    const int* __restrict__ src, const int* __restrict__ dst,
    int* __restrict__ cursor, int* __restrict__ sorted_src, int E)
{
    int i = blockIdx.x * blockDim.x + threadIdx.x;
    int stride = gridDim.x * blockDim.x;
    for (; i < E; i += stride) {
        int d = dst[i];
        int pos = atomicAdd(&cursor[d], 1);
        atomicExch(&sorted_src[pos], src[i]);
    }
}

// ---------------- per-layer kernels ----------------

// h = hin @ W (K x 64), al_s = h.a_src, al_d = h.a_dst. LDS-staged W.
// One wave per node (grid-stride). Lane c owns output channel c.
template<int K>
__global__ __launch_bounds__(256) void gemm_att_lds_kernel(
    const float* __restrict__ hin, const float* __restrict__ W,
    const float* __restrict__ a_src, const float* __restrict__ a_dst,
    float* __restrict__ hout, float* __restrict__ al_s, float* __restrict__ al_d,
    int n_nodes)
{
    __shared__ float Wl[K * HID];
    for (int i = threadIdx.x; i < K * HID; i += blockDim.x) Wl[i] = W[i];
    __syncthreads();

    const int lane = threadIdx.x & 63;
    const int wib  = threadIdx.x >> 6;
    const int wpb  = blockDim.x >> 6;
    int wid = blockIdx.x * wpb + wib;
    int nw  = gridDim.x * wpb;

    const float as = a_src[lane];
    const float ad = a_dst[lane];

    for (int nn = wid; nn < n_nodes; nn += nw) {
        const float* xr = hin + (size_t)nn * K;
        float acc = 0.f;
        #pragma unroll 8
        for (int k = 0; k < K; ++k)
            acc = fmaf(xr[k], Wl[k * HID + lane], acc);

        hout[(size_t)nn * HID + lane] = acc;

        float ps = acc * as, pd = acc * ad;
        #pragma unroll
        for (int off = 32; off; off >>= 1) {
            ps += __shfl_xor(ps, off);
            pd += __shfl_xor(pd, off);
        }
        if (lane == 0) {
            al_s[nn] = ps;
            al_d[nn] = pd;
        }
    }
}

// K=64 register version: W column in 64 VGPRs, row broadcast via shfl.
__global__ __launch_bounds__(256) void gemm_att_reg64_kernel(
    const float* __restrict__ hin, const float* __restrict__ W,
    const float* __restrict__ a_src, const float* __restrict__ a_dst,
    float* __restrict__ hout, float* __restrict__ al_s, float* __restrict__ al_d,
    int n_nodes)
{
    const int lane = threadIdx.x & 63;
    const int wib  = threadIdx.x >> 6;
    const int wpb  = blockDim.x >> 6;
    int wid = blockIdx.x * wpb + wib;
    int nw  = gridDim.x * wpb;

    float wreg[64];
    #pragma unroll
    for (int k = 0; k < 64; ++k) wreg[k] = W[k * HID + lane];

    const float as = a_src[lane];
    const float ad = a_dst[lane];

    for (int nn = wid; nn < n_nodes; nn += nw) {
        float r = hin[(size_t)nn * 64 + lane];
        float acc = 0.f;
        #pragma unroll
        for (int k = 0; k < 64; ++k)
            acc = fmaf(__shfl(r, k), wreg[k], acc);

        hout[(size_t)nn * HID + lane] = acc;

        float ps = acc * as, pd = acc * ad;
        #pragma unroll
        for (int off = 32; off; off >>= 1) {
            ps += __shfl_xor(ps, off);
            pd += __shfl_xor(pd, off);
        }
        if (lane == 0) {
            al_s[nn] = ps;
            al_d[nn] = pd;
        }
    }
}

// One wave per dst node. Phase 1: lane-parallel segment max.
// Phase 2: FOUR edges per iteration (quarter-wave per edge, float4 channel
// quad per lane) -> each wave instruction gathers 1KB covering 4 edges.
// Quarters combined via shfl_xor(16|32). Fused divide+bias+leaky (+head).
template<bool FUSE_HEAD>
__global__ __launch_bounds__(256) void node_agg_kernel(
    const int* __restrict__ offsets, const int* __restrict__ sorted_src,
    const float* __restrict__ al_s, const float* __restrict__ al_d,
    const float* __restrict__ h, const float* __restrict__ b,
    float* __restrict__ hout,
    const float* __restrict__ Wout, const float* __restrict__ bout,
    float* __restrict__ out, int n_nodes)
{
    const int lane = threadIdx.x & 63;
    const int q    = lane >> 4;        // quarter: which edge of the 4
    const int ch   = (lane & 15) * 4;  // float4 channel quad
    const int wib  = threadIdx.x >> 6;
    const int wpb  = blockDim.x >> 6;
    int wid = blockIdx.x * wpb + wib;
    int nw  = gridDim.x * wpb;

    const float4 bc = *(const float4*)&b[ch];
    const float4 wc = FUSE_HEAD ? *(const float4*)&Wout[ch] : float4{0.f,0.f,0.f,0.f};

    for (int d = wid; d < n_nodes; d += nw) {
        const float ald = al_d[d];
        float e0 = al_s[d] + ald;           // self-loop logit
        e0 = (e0 > 0.f) ? e0 : LR_ATT * e0;

        const int k0 = offsets[d];
        const int k1 = offsets[d + 1];

        // ---- phase 1: full-wave lane-parallel max ----
        float lm = e0;
        for (int k = k0 + lane; k < k1; k += 64) {
            int s = sorted_src[k];
            float e = al_s[s] + ald;
            e = (e > 0.f) ? e : LR_ATT * e;
            lm = fmaxf(lm, e);
        }
        #pragma unroll
        for (int off = 32; off; off >>= 1)
            lm = fmaxf(lm, __shfl_xor(lm, off));
        const float m = lm;

        // ---- phase 2: 4 edges/iteration, branch-free ----
        float ex0 = (q == 0) ? __expf(e0 - m) : 0.f;  // self-loop in quarter 0
        float sum = ex0;
        const float4 hd = *(const float4*)&h[(size_t)d * HID + ch];
        float4 acc;
        acc.x = ex0 * hd.x; acc.y = ex0 * hd.y;
        acc.z = ex0 * hd.z; acc.w = ex0 * hd.w;

        #pragma unroll 2
        for (int k = k0; k < k1; k += 4) {
            int kk = k + q;
            bool valid = (kk < k1);
            int s = valid ? sorted_src[kk] : d;
            float e = al_s[s] + ald;
            e = (e > 0.f) ? e : LR_ATT * e;
            float ex = valid ? __expf(e - m) : 0.f;
            const float4 hv = *(const float4*)&h[(size_t)s * HID + ch];
            acc.x = fmaf(ex, hv.x, acc.x);
            acc.y = fmaf(ex, hv.y, acc.y);
            acc.z = fmaf(ex, hv.z, acc.z);
            acc.w = fmaf(ex, hv.w, acc.w);
            sum += ex;
        }

        // ---- combine the four quarters (butterfly keeps all lanes valid) ----
        #pragma unroll
        for (int off = 16; off <= 32; off <<= 1) {
            acc.x += __shfl_xor(acc.x, off);
            acc.y += __shfl_xor(acc.y, off);
            acc.z += __shfl_xor(acc.z, off);
            acc.w += __shfl_xor(acc.w, off);
            sum   += __shfl_xor(sum, off);
        }

        float inv = 1.f / sum;
        float4 v;
        v.x = fmaf(acc.x, inv, bc.x); v.y = fmaf(acc.y, inv, bc.y);
        v.z = fmaf(acc.z, inv, bc.z); v.w = fmaf(acc.w, inv, bc.w);
        v.x = (v.x > 0.f) ? v.x : LR_ACT * v.x;
        v.y = (v.y > 0.f) ? v.y : LR_ACT * v.y;
        v.z = (v.z > 0.f) ? v.z : LR_ACT * v.z;
        v.w = (v.w > 0.f) ? v.w : LR_ACT * v.w;

        if (!FUSE_HEAD) {
            if (lane < 16) *(float4*)&hout[(size_t)d * HID + ch] = v;
        } else {
            float t = v.x * wc.x + v.y * wc.y + v.z * wc.z + v.w * wc.w;
            #pragma unroll
            for (int off = 8; off; off >>= 1) t += __shfl_xor(t, off);
            if (lane == 0) out[d] = t + bout[0];
        }
    }
}

extern "C" void kernel_launch(void* const* d_in, const int* in_sizes, int n_in,
                              void* d_out, int out_size, void* d_ws, size_t ws_size,
                              hipStream_t stream)
{
    const float* x      = (const float*)d_in[0];
    const int*   ei     = (const int*)  d_in[1];
    const float* W1     = (const float*)d_in[2];
    const float* a_src1 = (const float*)d_in[3];
    const float* a_dst1 = (const float*)d_in[4];
    const float* b1     = (const float*)d_in[5];
    const float* W2     = (const float*)d_in[6];
    const float* a_src2 = (const float*)d_in[7];
    const float* a_dst2 = (const float*)d_in[8];
    const float* b2     = (const float*)d_in[9];
    const float* W3     = (const float*)d_in[10];
    const float* a_src3 = (const float*)d_in[11];
    const float* a_dst3 = (const float*)d_in[12];
    const float* b3     = (const float*)d_in[13];
    const float* W_out  = (const float*)d_in[14];
    const float* b_out  = (const float*)d_in[15];
    float* out = (float*)d_out;

    const int n = out_size;           // 50000 nodes
    const int E = in_sizes[1] / 2;    // 1.6M edges

    const int* src = ei;
    const int* dst = ei + E;

    // workspace layout
    float* ws   = (float*)d_ws;
    float* hA   = ws;                        // n*64
    float* hB   = hA + (size_t)n * HID;      // n*64
    float* al_s = hB + (size_t)n * HID;      // n
    float* al_d = al_s + n;                  // n
    int* counts     = (int*)(al_d + n);      // n
    int* offsets    = counts + n;            // n+1
    int* cursor     = offsets + (n + 1);     // n
    int* sorted_src = cursor + n;            // E

    dim3 blk(256);
    const int gemm_grid = 1024;
    const int edge_grid = 4096;
    const int node_grid = (n + 3) / 4;       // 4 waves/block, 1 wave/node

    // ---- CSR build (graph is layer-invariant) ----
    hipMemsetAsync(counts, 0, (size_t)n * sizeof(int), stream);
    count_kernel<<<edge_grid, blk, 0, stream>>>(dst, counts, E);
    scan_kernel<<<1, SCAN_NT, 0, stream>>>(counts, offsets, cursor, n);
    scatter_kernel<<<edge_grid, blk, 0, stream>>>(src, dst, cursor, sorted_src, E);

    // ---- layer 1 (K = 128) ----
    gemm_att_lds_kernel<128><<<gemm_grid, blk, 0, stream>>>(x, W1, a_src1, a_dst1,
        hA, al_s, al_d, n);
    node_agg_kernel<false><<<node_grid, blk, 0, stream>>>(offsets, sorted_src,
        al_s, al_d, hA, b1, hB, nullptr, nullptr, nullptr, n);

    // ---- layer 2 (K = 64) ----
    gemm_att_reg64_kernel<<<gemm_grid, blk, 0, stream>>>(hB, W2, a_src2, a_dst2,
        hA, al_s, al_d, n);
    node_agg_kernel<false><<<node_grid, blk, 0, stream>>>(offsets, sorted_src,
        al_s, al_d, hA, b2, hB, nullptr, nullptr, nullptr, n);

    // ---- layer 3 (K = 64) + fused output head ----
    gemm_att_reg64_kernel<<<gemm_grid, blk, 0, stream>>>(hB, W3, a_src3, a_dst3,
        hA, al_s, al_d, n);
    node_agg_kernel<true><<<node_grid, blk, 0, stream>>>(offsets, sorted_src,
        al_s, al_d, hA, b3, nullptr, W_out, b_out, out, n);
}

// Round 18
// 596.364 us; speedup vs baseline: 1.1680x; 1.1680x over previous
//
#include <hip/hip_runtime.h>
#include <math.h>

#define HID 64
#define LR_ATT 0.2f
#define LR_ACT 0.01f
#define SCAN_NT 1024

// ---------------- CSR build (once per call; graph shared by all 3 layers) ----------------

__global__ __launch_bounds__(256) void count_kernel(
    const int* __restrict__ dst, int* __restrict__ counts, int E)
{
    int i = blockIdx.x * blockDim.x + threadIdx.x;
    int stride = gridDim.x * blockDim.x;
    for (; i < E; i += stride) atomicAdd(&counts[dst[i]], 1);
}

// Single-block exclusive scan of counts[0..n) -> offsets[0..n], plus cursor copy.
__global__ __launch_bounds__(SCAN_NT) void scan_kernel(
    const int* __restrict__ counts, int* __restrict__ offsets,
    int* __restrict__ cursor, int n)
{
    __shared__ int sdata[SCAN_NT];
    const int t = threadIdx.x;
    const int C = (n + SCAN_NT - 1) / SCAN_NT;
    const int beg = t * C;
    const int end = min(n, beg + C);

    int local = 0;
    for (int i = beg; i < end; ++i) local += counts[i];
    sdata[t] = local;
    __syncthreads();
    for (int off = 1; off < SCAN_NT; off <<= 1) {
        int v = (t >= off) ? sdata[t - off] : 0;
        __syncthreads();
        sdata[t] += v;
        __syncthreads();
    }
    int run = sdata[t] - local;
    for (int i = beg; i < end; ++i) {
        offsets[i] = run;
        cursor[i]  = run;
        run += counts[i];
    }
    if (end == n && beg <= n) offsets[n] = run;
}

// Split scatter: pass A reserves slots (dependent atomic only), pass B writes
// (no dependency -> full memory-level parallelism on the random stores).
__global__ __launch_bounds__(256) void scatter_pos_kernel(
    const int* __restrict__ dst, int* __restrict__ cursor,
    int* __restrict__ pos, int E)
{
    int i = blockIdx.x * blockDim.x + threadIdx.x;
    int stride = gridDim.x * blockDim.x;
    for (; i < E; i += stride)
        pos[i] = atomicAdd(&cursor[dst[i]], 1);
}

__global__ __launch_bounds__(256) void scatter_write_kernel(
    const int* __restrict__ src, const int* __restrict__ pos,
    int* __restrict__ sorted_src, int E)
{
    int i = blockIdx.x * blockDim.x + threadIdx.x;
    int stride = gridDim.x * blockDim.x;
    for (; i < E; i += stride)
        sorted_src[pos[i]] = src[i];
}

// ---------------- per-layer kernels ----------------

// h = hin @ W (K x 64), al_s = h.a_src, al_d = h.a_dst. LDS-staged W.
template<int K>
__global__ __launch_bounds__(256) void gemm_att_lds_kernel(
    const float* __restrict__ hin, const float* __restrict__ W,
    const float* __restrict__ a_src, const float* __restrict__ a_dst,
    float* __restrict__ hout, float* __restrict__ al_s, float* __restrict__ al_d,
    int n_nodes)
{
    __shared__ float Wl[K * HID];
    for (int i = threadIdx.x; i < K * HID; i += blockDim.x) Wl[i] = W[i];
    __syncthreads();

    const int lane = threadIdx.x & 63;
    const int wib  = threadIdx.x >> 6;
    const int wpb  = blockDim.x >> 6;
    int wid = blockIdx.x * wpb + wib;
    int nw  = gridDim.x * wpb;

    const float as = a_src[lane];
    const float ad = a_dst[lane];

    for (int nn = wid; nn < n_nodes; nn += nw) {
        const float* xr = hin + (size_t)nn * K;
        float acc = 0.f;
        #pragma unroll 8
        for (int k = 0; k < K; ++k)
            acc = fmaf(xr[k], Wl[k * HID + lane], acc);

        hout[(size_t)nn * HID + lane] = acc;

        float ps = acc * as, pd = acc * ad;
        #pragma unroll
        for (int off = 32; off; off >>= 1) {
            ps += __shfl_xor(ps, off);
            pd += __shfl_xor(pd, off);
        }
        if (lane == 0) {
            al_s[nn] = ps;
            al_d[nn] = pd;
        }
    }
}

// K=64 register version: W column in 64 VGPRs, row broadcast via shfl.
__global__ __launch_bounds__(256) void gemm_att_reg64_kernel(
    const float* __restrict__ hin, const float* __restrict__ W,
    const float* __restrict__ a_src, const float* __restrict__ a_dst,
    float* __restrict__ hout, float* __restrict__ al_s, float* __restrict__ al_d,
    int n_nodes)
{
    const int lane = threadIdx.x & 63;
    const int wib  = threadIdx.x >> 6;
    const int wpb  = blockDim.x >> 6;
    int wid = blockIdx.x * wpb + wib;
    int nw  = gridDim.x * wpb;

    float wreg[64];
    #pragma unroll
    for (int k = 0; k < 64; ++k) wreg[k] = W[k * HID + lane];

    const float as = a_src[lane];
    const float ad = a_dst[lane];

    for (int nn = wid; nn < n_nodes; nn += nw) {
        float r = hin[(size_t)nn * 64 + lane];
        float acc = 0.f;
        #pragma unroll
        for (int k = 0; k < 64; ++k)
            acc = fmaf(__shfl(r, k), wreg[k], acc);

        hout[(size_t)nn * HID + lane] = acc;

        float ps = acc * as, pd = acc * ad;
        #pragma unroll
        for (int off = 32; off; off >>= 1) {
            ps += __shfl_xor(ps, off);
            pd += __shfl_xor(pd, off);
        }
        if (lane == 0) {
            al_s[nn] = ps;
            al_d[nn] = pd;
        }
    }
}

// One wave per dst node. Phase 1: lane ℓ preloads edge ℓ's src + logit
// (coalesced), wave-max, p = exp(e-m) per lane, denominator via ONE wave
// reduce -> softmax fully resolved before the gather loop. Phase 2: quarter-
// wave per edge; s,p broadcast by shfl (no memory deps), one float4 gather +
// 4 fma per quarter per iteration. Degree>64 handled by a rare tail loop.
template<bool FUSE_HEAD>
__global__ __launch_bounds__(256) void node_agg_kernel(
    const int* __restrict__ offsets, const int* __restrict__ sorted_src,
    const float* __restrict__ al_s, const float* __restrict__ al_d,
    const float* __restrict__ h, const float* __restrict__ b,
    float* __restrict__ hout,
    const float* __restrict__ Wout, const float* __restrict__ bout,
    float* __restrict__ out, int n_nodes)
{
    const int lane = threadIdx.x & 63;
    const int q    = lane >> 4;        // quarter: which edge of the 4
    const int ch   = (lane & 15) * 4;  // float4 channel quad
    const int wib  = threadIdx.x >> 6;
    const int wpb  = blockDim.x >> 6;
    int wid = blockIdx.x * wpb + wib;
    int nw  = gridDim.x * wpb;

    const float4 bc = *(const float4*)&b[ch];
    const float4 wc = FUSE_HEAD ? *(const float4*)&Wout[ch] : float4{0.f,0.f,0.f,0.f};

    for (int d = wid; d < n_nodes; d += nw) {
        const float ald = al_d[d];
        float e0 = al_s[d] + ald;           // self-loop logit
        e0 = (e0 > 0.f) ? e0 : LR_ATT * e0;

        const int k0  = offsets[d];
        const int k1  = offsets[d + 1];
        const int deg = k1 - k0;

        // ---- phase 1: preload + max + softmax weights + denominator ----
        int   sA = d;
        float eA = __int_as_float(0xff800000);  // -inf
        if (lane < deg) {
            sA = sorted_src[k0 + lane];
            float e = al_s[sA] + ald;
            eA = (e > 0.f) ? e : LR_ATT * e;
        }
        float lm = fmaxf(e0, eA);
        for (int k = k0 + 64 + lane; k < k1; k += 64) {  // rare: deg > 64
            int s = sorted_src[k];
            float e = al_s[s] + ald;
            e = (e > 0.f) ? e : LR_ATT * e;
            lm = fmaxf(lm, e);
        }
        #pragma unroll
        for (int off = 32; off; off >>= 1)
            lm = fmaxf(lm, __shfl_xor(lm, off));
        const float m = lm;

        const float ex0 = __expf(e0 - m);
        float pA = (lane < deg) ? __expf(eA - m) : 0.f;
        float ssum = pA;
        #pragma unroll
        for (int off = 32; off; off >>= 1) ssum += __shfl_xor(ssum, off);
        float sum = ssum + ex0;                 // wave-uniform denominator

        // ---- phase 2: gather-accumulate, 4 edges / iteration ----
        const float4 hd = *(const float4*)&h[(size_t)d * HID + ch];
        float exq = (q == 0) ? ex0 : 0.f;       // self-loop in quarter 0
        float4 acc;
        acc.x = exq * hd.x; acc.y = exq * hd.y;
        acc.z = exq * hd.z; acc.w = exq * hd.w;

        const int mainN = min(deg, 64);
        for (int k = 0; k < mainN; k += 4) {
            int   s = __shfl(sA, k + q);        // broadcast, no memory dep
            float p = __shfl(pA, k + q);        // 0 beyond deg
            const float4 hv = *(const float4*)&h[(size_t)s * HID + ch];
            acc.x = fmaf(p, hv.x, acc.x);
            acc.y = fmaf(p, hv.y, acc.y);
            acc.z = fmaf(p, hv.z, acc.z);
            acc.w = fmaf(p, hv.w, acc.w);
        }

        // rare tail: deg > 64
        float sumX = 0.f;
        for (int k = k0 + 64; k < k1; k += 4) {
            int kk = k + q;
            bool valid = (kk < k1);
            int s = valid ? sorted_src[kk] : d;
            float e = al_s[s] + ald;
            e = (e > 0.f) ? e : LR_ATT * e;
            float ex = valid ? __expf(e - m) : 0.f;
            const float4 hv = *(const float4*)&h[(size_t)s * HID + ch];
            acc.x = fmaf(ex, hv.x, acc.x);
            acc.y = fmaf(ex, hv.y, acc.y);
            acc.z = fmaf(ex, hv.z, acc.z);
            acc.w = fmaf(ex, hv.w, acc.w);
            sumX += ex;
        }

        // ---- combine the four quarters ----
        #pragma unroll
        for (int off = 16; off <= 32; off <<= 1) {
            acc.x += __shfl_xor(acc.x, off);
            acc.y += __shfl_xor(acc.y, off);
            acc.z += __shfl_xor(acc.z, off);
            acc.w += __shfl_xor(acc.w, off);
            sumX  += __shfl_xor(sumX, off);
        }
        sum += sumX;

        float inv = 1.f / sum;
        float4 v;
        v.x = fmaf(acc.x, inv, bc.x); v.y = fmaf(acc.y, inv, bc.y);
        v.z = fmaf(acc.z, inv, bc.z); v.w = fmaf(acc.w, inv, bc.w);
        v.x = (v.x > 0.f) ? v.x : LR_ACT * v.x;
        v.y = (v.y > 0.f) ? v.y : LR_ACT * v.y;
        v.z = (v.z > 0.f) ? v.z : LR_ACT * v.z;
        v.w = (v.w > 0.f) ? v.w : LR_ACT * v.w;

        if (!FUSE_HEAD) {
            if (lane < 16) *(float4*)&hout[(size_t)d * HID + ch] = v;
        } else {
            float t = v.x * wc.x + v.y * wc.y + v.z * wc.z + v.w * wc.w;
            #pragma unroll
            for (int off = 8; off; off >>= 1) t += __shfl_xor(t, off);
            if (lane == 0) out[d] = t + bout[0];
        }
    }
}

extern "C" void kernel_launch(void* const* d_in, const int* in_sizes, int n_in,
                              void* d_out, int out_size, void* d_ws, size_t ws_size,
                              hipStream_t stream)
{
    const float* x      = (const float*)d_in[0];
    const int*   ei     = (const int*)  d_in[1];
    const float* W1     = (const float*)d_in[2];
    const float* a_src1 = (const float*)d_in[3];
    const float* a_dst1 = (const float*)d_in[4];
    const float* b1     = (const float*)d_in[5];
    const float* W2     = (const float*)d_in[6];
    const float* a_src2 = (const float*)d_in[7];
    const float* a_dst2 = (const float*)d_in[8];
    const float* b2     = (const float*)d_in[9];
    const float* W3     = (const float*)d_in[10];
    const float* a_src3 = (const float*)d_in[11];
    const float* a_dst3 = (const float*)d_in[12];
    const float* b3     = (const float*)d_in[13];
    const float* W_out  = (const float*)d_in[14];
    const float* b_out  = (const float*)d_in[15];
    float* out = (float*)d_out;

    const int n = out_size;           // 50000 nodes
    const int E = in_sizes[1] / 2;    // 1.6M edges

    const int* src = ei;
    const int* dst = ei + E;

    // workspace layout
    float* ws   = (float*)d_ws;
    float* hA   = ws;                        // n*64
    float* hB   = hA + (size_t)n * HID;      // n*64
    float* al_s = hB + (size_t)n * HID;      // n
    float* al_d = al_s + n;                  // n
    int* counts     = (int*)(al_d + n);      // n
    int* offsets    = counts + n;            // n+1
    int* cursor     = offsets + (n + 1);     // n
    int* sorted_src = cursor + n;            // E
    int* pos        = sorted_src + E;        // E

    dim3 blk(256);
    const int gemm_grid = 1024;
    const int edge_grid = 4096;
    const int node_grid = (n + 3) / 4;       // 4 waves/block, 1 wave/node

    // ---- CSR build (graph is layer-invariant) ----
    (void)hipMemsetAsync(counts, 0, (size_t)n * sizeof(int), stream);
    count_kernel<<<edge_grid, blk, 0, stream>>>(dst, counts, E);
    scan_kernel<<<1, SCAN_NT, 0, stream>>>(counts, offsets, cursor, n);
    scatter_pos_kernel<<<edge_grid, blk, 0, stream>>>(dst, cursor, pos, E);
    scatter_write_kernel<<<edge_grid, blk, 0, stream>>>(src, pos, sorted_src, E);

    // ---- layer 1 (K = 128) ----
    gemm_att_lds_kernel<128><<<gemm_grid, blk, 0, stream>>>(x, W1, a_src1, a_dst1,
        hA, al_s, al_d, n);
    node_agg_kernel<false><<<node_grid, blk, 0, stream>>>(offsets, sorted_src,
        al_s, al_d, hA, b1, hB, nullptr, nullptr, nullptr, n);

    // ---- layer 2 (K = 64) ----
    gemm_att_reg64_kernel<<<gemm_grid, blk, 0, stream>>>(hB, W2, a_src2, a_dst2,
        hA, al_s, al_d, n);
    node_agg_kernel<false><<<node_grid, blk, 0, stream>>>(offsets, sorted_src,
        al_s, al_d, hA, b2, hB, nullptr, nullptr, nullptr, n);

    // ---- layer 3 (K = 64) + fused output head ----
    gemm_att_reg64_kernel<<<gemm_grid, blk, 0, stream>>>(hB, W3, a_src3, a_dst3,
        hA, al_s, al_d, n);
    node_agg_kernel<true><<<node_grid, blk, 0, stream>>>(offsets, sorted_src,
        al_s, al_d, hA, b3, nullptr, W_out, b_out, out, n);
}

// Round 20
// 429.543 us; speedup vs baseline: 1.6216x; 1.3884x over previous
//
#include <hip/hip_runtime.h>
#include <math.h>

#define HID 64
#define LR_ATT 0.2f
#define LR_ACT 0.01f
#define SCHUNK 1024   // elements per scan block

// ---------------- CSR build (once per call; graph shared by all 3 layers) ----------------

// Pass 1: per-dst count AND within-bucket rank in one atomic.
__global__ __launch_bounds__(256) void count_rank_kernel(
    const int* __restrict__ dst, int* __restrict__ counts,
    int* __restrict__ rank, int E)
{
    int i = blockIdx.x * blockDim.x + threadIdx.x;
    int stride = gridDim.x * blockDim.x;
    for (; i < E; i += stride)
        rank[i] = atomicAdd(&counts[dst[i]], 1);
}

// Hierarchical scan (n up to 256*SCHUNK): reduce -> top scan -> apply.
__global__ __launch_bounds__(256) void scan_reduce_kernel(
    const int* __restrict__ counts, int* __restrict__ part, int n)
{
    __shared__ int sdata[256];
    const int b = blockIdx.x, t = threadIdx.x;
    const int base = b * SCHUNK;
    int sum = 0;
    for (int i = base + t; i < n && i < base + SCHUNK; i += 256) sum += counts[i];
    sdata[t] = sum;
    __syncthreads();
    for (int off = 128; off; off >>= 1) {
        if (t < off) sdata[t] += sdata[t + off];
        __syncthreads();
    }
    if (t == 0) part[b] = sdata[0];
}

__global__ __launch_bounds__(256) void scan_top_kernel(
    int* __restrict__ part, int nPart, int* __restrict__ offsets, int n)
{
    __shared__ int sdata[256];
    const int t = threadIdx.x;
    int v = (t < nPart) ? part[t] : 0;
    sdata[t] = v;
    __syncthreads();
    for (int off = 1; off < 256; off <<= 1) {
        int u = (t >= off) ? sdata[t - off] : 0;
        __syncthreads();
        sdata[t] += u;
        __syncthreads();
    }
    if (t < nPart) part[t] = sdata[t] - v;     // exclusive block prefix
    if (t == 255) offsets[n] = sdata[255];     // total == E
}

__global__ __launch_bounds__(256) void scan_apply_kernel(
    const int* __restrict__ counts, const int* __restrict__ part,
    int* __restrict__ offsets, int n)
{
    __shared__ int sdata[256];
    const int b = blockIdx.x, t = threadIdx.x;
    const int i0 = b * SCHUNK + t * 4;
    int c[4];
    int s = 0;
    #pragma unroll
    for (int j = 0; j < 4; ++j) {
        int i = i0 + j;
        c[j] = (i < n) ? counts[i] : 0;
        s += c[j];
    }
    sdata[t] = s;
    __syncthreads();
    for (int off = 1; off < 256; off <<= 1) {
        int u = (t >= off) ? sdata[t - off] : 0;
        __syncthreads();
        sdata[t] += u;
        __syncthreads();
    }
    int run = part[b] + sdata[t] - s;          // exclusive base for this thread
    #pragma unroll
    for (int j = 0; j < 4; ++j) {
        int i = i0 + j;
        if (i < n) offsets[i] = run;
        run += c[j];
    }
}

// Pass 2: independent random writes (full MLP, no atomic dependency).
__global__ __launch_bounds__(256) void scatter_write_kernel(
    const int* __restrict__ src, const int* __restrict__ dst,
    const int* __restrict__ rank, const int* __restrict__ offsets,
    int* __restrict__ sorted_src, int E)
{
    int i = blockIdx.x * blockDim.x + threadIdx.x;
    int stride = gridDim.x * blockDim.x;
    for (; i < E; i += stride)
        sorted_src[offsets[dst[i]] + rank[i]] = src[i];
}

// ---------------- per-layer kernels ----------------

// h = hin @ W (K x 64), al_s = h.a_src, al_d = h.a_dst. LDS-staged W.
template<int K>
__global__ __launch_bounds__(256) void gemm_att_lds_kernel(
    const float* __restrict__ hin, const float* __restrict__ W,
    const float* __restrict__ a_src, const float* __restrict__ a_dst,
    float* __restrict__ hout, float* __restrict__ al_s, float* __restrict__ al_d,
    int n_nodes)
{
    __shared__ float Wl[K * HID];
    for (int i = threadIdx.x; i < K * HID; i += blockDim.x) Wl[i] = W[i];
    __syncthreads();

    const int lane = threadIdx.x & 63;
    const int wib  = threadIdx.x >> 6;
    const int wpb  = blockDim.x >> 6;
    int wid = blockIdx.x * wpb + wib;
    int nw  = gridDim.x * wpb;

    const float as = a_src[lane];
    const float ad = a_dst[lane];

    for (int nn = wid; nn < n_nodes; nn += nw) {
        const float* xr = hin + (size_t)nn * K;
        float acc = 0.f;
        #pragma unroll 8
        for (int k = 0; k < K; ++k)
            acc = fmaf(xr[k], Wl[k * HID + lane], acc);

        hout[(size_t)nn * HID + lane] = acc;

        float ps = acc * as, pd = acc * ad;
        #pragma unroll
        for (int off = 32; off; off >>= 1) {
            ps += __shfl_xor(ps, off);
            pd += __shfl_xor(pd, off);
        }
        if (lane == 0) {
            al_s[nn] = ps;
            al_d[nn] = pd;
        }
    }
}

// K=64 register version: W column in 64 VGPRs, row broadcast via shfl.
__global__ __launch_bounds__(256) void gemm_att_reg64_kernel(
    const float* __restrict__ hin, const float* __restrict__ W,
    const float* __restrict__ a_src, const float* __restrict__ a_dst,
    float* __restrict__ hout, float* __restrict__ al_s, float* __restrict__ al_d,
    int n_nodes)
{
    const int lane = threadIdx.x & 63;
    const int wib  = threadIdx.x >> 6;
    const int wpb  = blockDim.x >> 6;
    int wid = blockIdx.x * wpb + wib;
    int nw  = gridDim.x * wpb;

    float wreg[64];
    #pragma unroll
    for (int k = 0; k < 64; ++k) wreg[k] = W[k * HID + lane];

    const float as = a_src[lane];
    const float ad = a_dst[lane];

    for (int nn = wid; nn < n_nodes; nn += nw) {
        float r = hin[(size_t)nn * 64 + lane];
        float acc = 0.f;
        #pragma unroll
        for (int k = 0; k < 64; ++k)
            acc = fmaf(__shfl(r, k), wreg[k], acc);

        hout[(size_t)nn * HID + lane] = acc;

        float ps = acc * as, pd = acc * ad;
        #pragma unroll
        for (int off = 32; off; off >>= 1) {
            ps += __shfl_xor(ps, off);
            pd += __shfl_xor(pd, off);
        }
        if (lane == 0) {
            al_s[nn] = ps;
            al_d[nn] = pd;
        }
    }
}

// One wave per dst node. Phase 1: lane ℓ preloads edge ℓ's src + logit
// (coalesced), wave-max, p = exp(e-m) per lane, denominator via ONE wave
// reduce -> softmax fully resolved before the gather loop. Phase 2: quarter-
// wave per edge; s,p broadcast by shfl (no memory deps), one float4 gather +
// 4 fma per quarter per iteration. Degree>64 handled by a rare tail loop.
template<bool FUSE_HEAD>
__global__ __launch_bounds__(256) void node_agg_kernel(
    const int* __restrict__ offsets, const int* __restrict__ sorted_src,
    const float* __restrict__ al_s, const float* __restrict__ al_d,
    const float* __restrict__ h, const float* __restrict__ b,
    float* __restrict__ hout,
    const float* __restrict__ Wout, const float* __restrict__ bout,
    float* __restrict__ out, int n_nodes)
{
    const int lane = threadIdx.x & 63;
    const int q    = lane >> 4;        // quarter: which edge of the 4
    const int ch   = (lane & 15) * 4;  // float4 channel quad
    const int wib  = threadIdx.x >> 6;
    const int wpb  = blockDim.x >> 6;
    int wid = blockIdx.x * wpb + wib;
    int nw  = gridDim.x * wpb;

    const float4 bc = *(const float4*)&b[ch];
    const float4 wc = FUSE_HEAD ? *(const float4*)&Wout[ch] : float4{0.f,0.f,0.f,0.f};

    for (int d = wid; d < n_nodes; d += nw) {
        const float ald = al_d[d];
        float e0 = al_s[d] + ald;           // self-loop logit
        e0 = (e0 > 0.f) ? e0 : LR_ATT * e0;

        const int k0  = offsets[d];
        const int k1  = offsets[d + 1];
        const int deg = k1 - k0;

        // ---- phase 1: preload + max + softmax weights + denominator ----
        int   sA = d;
        float eA = __int_as_float(0xff800000);  // -inf
        if (lane < deg) {
            sA = sorted_src[k0 + lane];
            float e = al_s[sA] + ald;
            eA = (e > 0.f) ? e : LR_ATT * e;
        }
        float lm = fmaxf(e0, eA);
        for (int k = k0 + 64 + lane; k < k1; k += 64) {  // rare: deg > 64
            int s = sorted_src[k];
            float e = al_s[s] + ald;
            e = (e > 0.f) ? e : LR_ATT * e;
            lm = fmaxf(lm, e);
        }
        #pragma unroll
        for (int off = 32; off; off >>= 1)
            lm = fmaxf(lm, __shfl_xor(lm, off));
        const float m = lm;

        const float ex0 = __expf(e0 - m);
        float pA = (lane < deg) ? __expf(eA - m) : 0.f;
        float ssum = pA;
        #pragma unroll
        for (int off = 32; off; off >>= 1) ssum += __shfl_xor(ssum, off);
        float sum = ssum + ex0;                 // wave-uniform denominator

        // ---- phase 2: gather-accumulate, 4 edges / iteration ----
        const float4 hd = *(const float4*)&h[(size_t)d * HID + ch];
        float exq = (q == 0) ? ex0 : 0.f;       // self-loop in quarter 0
        float4 acc;
        acc.x = exq * hd.x; acc.y = exq * hd.y;
        acc.z = exq * hd.z; acc.w = exq * hd.w;

        const int mainN = min(deg, 64);
        for (int k = 0; k < mainN; k += 4) {
            int   s = __shfl(sA, k + q);        // broadcast, no memory dep
            float p = __shfl(pA, k + q);        // 0 beyond deg
            const float4 hv = *(const float4*)&h[(size_t)s * HID + ch];
            acc.x = fmaf(p, hv.x, acc.x);
            acc.y = fmaf(p, hv.y, acc.y);
            acc.z = fmaf(p, hv.z, acc.z);
            acc.w = fmaf(p, hv.w, acc.w);
        }

        // rare tail: deg > 64
        float sumX = 0.f;
        for (int k = k0 + 64; k < k1; k += 4) {
            int kk = k + q;
            bool valid = (kk < k1);
            int s = valid ? sorted_src[kk] : d;
            float e = al_s[s] + ald;
            e = (e > 0.f) ? e : LR_ATT * e;
            float ex = valid ? __expf(e - m) : 0.f;
            const float4 hv = *(const float4*)&h[(size_t)s * HID + ch];
            acc.x = fmaf(ex, hv.x, acc.x);
            acc.y = fmaf(ex, hv.y, acc.y);
            acc.z = fmaf(ex, hv.z, acc.z);
            acc.w = fmaf(ex, hv.w, acc.w);
            sumX += ex;
        }

        // ---- combine the four quarters ----
        #pragma unroll
        for (int off = 16; off <= 32; off <<= 1) {
            acc.x += __shfl_xor(acc.x, off);
            acc.y += __shfl_xor(acc.y, off);
            acc.z += __shfl_xor(acc.z, off);
            acc.w += __shfl_xor(acc.w, off);
            sumX  += __shfl_xor(sumX, off);
        }
        sum += sumX;

        float inv = 1.f / sum;
        float4 v;
        v.x = fmaf(acc.x, inv, bc.x); v.y = fmaf(acc.y, inv, bc.y);
        v.z = fmaf(acc.z, inv, bc.z); v.w = fmaf(acc.w, inv, bc.w);
        v.x = (v.x > 0.f) ? v.x : LR_ACT * v.x;
        v.y = (v.y > 0.f) ? v.y : LR_ACT * v.y;
        v.z = (v.z > 0.f) ? v.z : LR_ACT * v.z;
        v.w = (v.w > 0.f) ? v.w : LR_ACT * v.w;

        if (!FUSE_HEAD) {
            if (lane < 16) *(float4*)&hout[(size_t)d * HID + ch] = v;
        } else {
            float t = v.x * wc.x + v.y * wc.y + v.z * wc.z + v.w * wc.w;
            #pragma unroll
            for (int off = 8; off; off >>= 1) t += __shfl_xor(t, off);
            if (lane == 0) out[d] = t + bout[0];
        }
    }
}

extern "C" void kernel_launch(void* const* d_in, const int* in_sizes, int n_in,
                              void* d_out, int out_size, void* d_ws, size_t ws_size,
                              hipStream_t stream)
{
    const float* x      = (const float*)d_in[0];
    const int*   ei     = (const int*)  d_in[1];
    const float* W1     = (const float*)d_in[2];
    const float* a_src1 = (const float*)d_in[3];
    const float* a_dst1 = (const float*)d_in[4];
    const float* b1     = (const float*)d_in[5];
    const float* W2     = (const float*)d_in[6];
    const float* a_src2 = (const float*)d_in[7];
    const float* a_dst2 = (const float*)d_in[8];
    const float* b2     = (const float*)d_in[9];
    const float* W3     = (const float*)d_in[10];
    const float* a_src3 = (const float*)d_in[11];
    const float* a_dst3 = (const float*)d_in[12];
    const float* b3     = (const float*)d_in[13];
    const float* W_out  = (const float*)d_in[14];
    const float* b_out  = (const float*)d_in[15];
    float* out = (float*)d_out;

    const int n = out_size;           // 50000 nodes
    const int E = in_sizes[1] / 2;    // 1.6M edges

    const int* src = ei;
    const int* dst = ei + E;

    // workspace layout
    float* ws   = (float*)d_ws;
    float* hA   = ws;                        // n*64
    float* hB   = hA + (size_t)n * HID;      // n*64
    float* al_s = hB + (size_t)n * HID;      // n
    float* al_d = al_s + n;                  // n
    int* counts     = (int*)(al_d + n);      // n
    int* offsets    = counts + n;            // n+1
    int* part       = offsets + (n + 1);     // 256
    int* rank       = part + 256;            // E
    int* sorted_src = rank + E;              // E

    dim3 blk(256);
    const int gemm_grid = 1024;
    const int edge_grid = 4096;
    const int node_grid = (n + 3) / 4;             // 4 waves/block, 1 wave/node
    const int nPart     = (n + SCHUNK - 1) / SCHUNK;  // 49 scan blocks

    // ---- CSR build (graph is layer-invariant) ----
    (void)hipMemsetAsync(counts, 0, (size_t)n * sizeof(int), stream);
    count_rank_kernel<<<edge_grid, blk, 0, stream>>>(dst, counts, rank, E);
    scan_reduce_kernel<<<nPart, blk, 0, stream>>>(counts, part, n);
    scan_top_kernel<<<1, blk, 0, stream>>>(part, nPart, offsets, n);
    scan_apply_kernel<<<nPart, blk, 0, stream>>>(counts, part, offsets, n);
    scatter_write_kernel<<<edge_grid, blk, 0, stream>>>(src, dst, rank, offsets,
        sorted_src, E);

    // ---- layer 1 (K = 128) ----
    gemm_att_lds_kernel<128><<<gemm_grid, blk, 0, stream>>>(x, W1, a_src1, a_dst1,
        hA, al_s, al_d, n);
    node_agg_kernel<false><<<node_grid, blk, 0, stream>>>(offsets, sorted_src,
        al_s, al_d, hA, b1, hB, nullptr, nullptr, nullptr, n);

    // ---- layer 2 (K = 64) ----
    gemm_att_reg64_kernel<<<gemm_grid, blk, 0, stream>>>(hB, W2, a_src2, a_dst2,
        hA, al_s, al_d, n);
    node_agg_kernel<false><<<node_grid, blk, 0, stream>>>(offsets, sorted_src,
        al_s, al_d, hA, b2, hB, nullptr, nullptr, nullptr, n);

    // ---- layer 3 (K = 64) + fused output head ----
    gemm_att_reg64_kernel<<<gemm_grid, blk, 0, stream>>>(hB, W3, a_src3, a_dst3,
        hA, al_s, al_d, n);
    node_agg_kernel<true><<<node_grid, blk, 0, stream>>>(offsets, sorted_src,
        al_s, al_d, hA, b3, nullptr, W_out, b_out, out, n);
}